// Round 1
// baseline (362.592 us; speedup 1.0000x reference)
//
#include <hip/hip_runtime.h>
#include <hip/hip_bf16.h>
#include <cstdint>
#include <cmath>

#define SEQ 2048
#define NH 16
#define DM 1024
#define BATCH 2

typedef short bf16x8 __attribute__((ext_vector_type(8)));
typedef float f32x4 __attribute__((ext_vector_type(4)));
typedef const void __attribute__((address_space(1)))* gas_t;
typedef void __attribute__((address_space(3)))* las_t;

static __device__ __forceinline__ unsigned short f2bf(float f) {
    union { __hip_bfloat16 h; unsigned short u; } cv;
    cv.h = __float2bfloat16(f);
    return cv.u;
}
static __device__ __forceinline__ float bf2f(unsigned short u) {
    union { unsigned short u; __hip_bfloat16 h; } cv;
    cv.u = u;
    return __bfloat162float(cv.h);
}

static __device__ __forceinline__ void gload_lds16(const void* g, void* l) {
    __builtin_amdgcn_global_load_lds(
        reinterpret_cast<gas_t>(reinterpret_cast<uintptr_t>(g)),
        reinterpret_cast<las_t>(reinterpret_cast<uintptr_t>(l)),
        16, 0, 0);
}

// ---------------- fp32 -> bf16 convert ----------------
__global__ void cvt_f32_bf16(const float* __restrict__ src,
                             unsigned short* __restrict__ dst, int n4) {
    int i = blockIdx.x * blockDim.x + threadIdx.x;
    if (i >= n4) return;
    float4 v = reinterpret_cast<const float4*>(src)[i];
    ushort4 o;
    o.x = f2bf(v.x); o.y = f2bf(v.y); o.z = f2bf(v.z); o.w = f2bf(v.w);
    reinterpret_cast<ushort4*>(dst)[i] = o;
}

// ---------------- bf16 GEMM: C[M][N] = A[M][K] * B[N][K]^T ----------------
// m97-style: 128x128 tile, BK=32, 4 waves (2x2), 4x4 16x16x32 frags per wave.
template<int OUT_BF16>
__global__ __launch_bounds__(256) void gemm_bt(
    const unsigned short* __restrict__ A,
    const unsigned short* __restrict__ B,
    void* __restrict__ C, int M, int N, int K) {
    __shared__ unsigned short As[128 * 32];
    __shared__ unsigned short Bs[128 * 32];
    const int tid = threadIdx.x;
    const int lane = tid & 63, wid = tid >> 6;
    const int wr = wid >> 1, wc = wid & 1;
    const int ln15 = lane & 15, kq = lane >> 4;
    const int bm = blockIdx.y, bn = blockIdx.x;

    f32x4 acc[4][4] = {};
    const int nk = K >> 5;
    for (int kt = 0; kt < nk; ++kt) {
        #pragma unroll
        for (int i = 0; i < 2; ++i) {
            int c = i * 256 + tid;
            int row = c >> 2, k8 = (c & 3) << 3;
            size_t gofsA = (size_t)(bm * 128 + row) * K + kt * 32 + k8;
            size_t gofsB = (size_t)(bn * 128 + row) * K + kt * 32 + k8;
            unsigned ldsoff = (unsigned)(i * 256 + wid * 64) * 16;  // wave-uniform
            gload_lds16(A + gofsA, (char*)As + ldsoff);
            gload_lds16(B + gofsB, (char*)Bs + ldsoff);
        }
        __syncthreads();
        bf16x8 af[4], bf[4];
        #pragma unroll
        for (int m = 0; m < 4; ++m)
            af[m] = *reinterpret_cast<const bf16x8*>(&As[(wr * 64 + m * 16 + ln15) * 32 + kq * 8]);
        #pragma unroll
        for (int n = 0; n < 4; ++n)
            bf[n] = *reinterpret_cast<const bf16x8*>(&Bs[(wc * 64 + n * 16 + ln15) * 32 + kq * 8]);
        #pragma unroll
        for (int m = 0; m < 4; ++m)
            #pragma unroll
            for (int n = 0; n < 4; ++n)
                acc[m][n] = __builtin_amdgcn_mfma_f32_16x16x32_bf16(af[m], bf[n], acc[m][n], 0, 0, 0);
        __syncthreads();
    }
    #pragma unroll
    for (int m = 0; m < 4; ++m) {
        #pragma unroll
        for (int n = 0; n < 4; ++n) {
            int col = bn * 128 + wc * 64 + n * 16 + ln15;
            #pragma unroll
            for (int j = 0; j < 4; ++j) {
                int row = bm * 128 + wr * 64 + m * 16 + kq * 4 + j;
                if constexpr (OUT_BF16 != 0)
                    ((unsigned short*)C)[(size_t)row * N + col] = f2bf(acc[m][n][j]);
                else
                    ((float*)C)[(size_t)row * N + col] = acc[m][n][j];
            }
        }
    }
}

// ---------------- RoPE + [B,S,H,D] -> [B,H,S,D] ----------------
__global__ __launch_bounds__(256) void rope_kernel(
    const unsigned short* __restrict__ Qt, const unsigned short* __restrict__ Kt,
    const int* __restrict__ pos,
    unsigned short* __restrict__ Qh, unsigned short* __restrict__ Kh) {
    int bs = blockIdx.x;            // b*SEQ + s
    int b = bs >> 11, s = bs & (SEQ - 1);
    float fpos = (float)pos[s];
    int t = threadIdx.x;
    #pragma unroll
    for (int p = t; p < 512; p += 256) {
        int h = p >> 5, i = p & 31;
        float freq = exp2f(-(float)i * (13.287712379549449f / 32.0f));  // theta^(-i/32)
        float ang = fpos * freq, sn, cs;
        sincosf(ang, &sn, &cs);
        size_t src = (size_t)bs * DM + h * 64 + 2 * i;
        size_t dst = ((size_t)(b * NH + h) * SEQ + s) * 64 + 2 * i;
        float q0 = bf2f(Qt[src]), q1 = bf2f(Qt[src + 1]);
        Qh[dst] = f2bf(q0 * cs - q1 * sn);
        Qh[dst + 1] = f2bf(q1 * cs + q0 * sn);
        float k0 = bf2f(Kt[src]), k1 = bf2f(Kt[src + 1]);
        Kh[dst] = f2bf(k0 * cs - k1 * sn);
        Kh[dst + 1] = f2bf(k1 * cs + k0 * sn);
    }
}

// ---------------- V: [B,S,H,64] -> [B,H,64,S] (tiled transpose) ----------------
__global__ __launch_bounds__(256) void vtrans_kernel(
    const unsigned short* __restrict__ V, unsigned short* __restrict__ Vo) {
    __shared__ unsigned short tile[64][65];
    int blk = blockIdx.x;           // (b*NH + h)*32 + st
    int st = blk & 31, bh = blk >> 5;
    int sb = st * 64;
    int t = threadIdx.x;
    int b = bh >> 4, h = bh & 15;
    #pragma unroll
    for (int u = t; u < 1024; u += 256) {
        int sl = u >> 4, d4 = (u & 15) << 2;
        ushort4 v = *reinterpret_cast<const ushort4*>(
            V + ((size_t)(b * SEQ + sb + sl) * NH + h) * 64 + d4);
        tile[sl][d4] = v.x; tile[sl][d4 + 1] = v.y;
        tile[sl][d4 + 2] = v.z; tile[sl][d4 + 3] = v.w;
    }
    __syncthreads();
    #pragma unroll
    for (int u = t; u < 1024; u += 256) {
        int d = u >> 4, s4 = (u & 15) << 2;
        ushort4 o;
        o.x = tile[s4][d]; o.y = tile[s4 + 1][d];
        o.z = tile[s4 + 2][d]; o.w = tile[s4 + 3][d];
        *reinterpret_cast<ushort4*>(Vo + ((size_t)bh * 64 + d) * SEQ + sb + s4) = o;
    }
}

// ---------------- causal flash attention ----------------
// one wave per (b,h, 16-q-row tile). Qh/Kh: [B,H,S,64]; Vt: [B,H,64,S]; Out: [B,S,H*64]
__global__ __launch_bounds__(64) void attn_kernel(
    const unsigned short* __restrict__ Qh, const unsigned short* __restrict__ Kh,
    const unsigned short* __restrict__ Vt, unsigned short* __restrict__ Out) {
    __shared__ unsigned short Plds[16 * 32];
    int bid = blockIdx.x;
    int qt = bid & 127, bh = bid >> 7;
    int qb = qt * 16;
    int lane = threadIdx.x;
    int ln15 = lane & 15, g = lane >> 4;

    const unsigned short* Qp = Qh + (size_t)bh * SEQ * 64;
    const unsigned short* Kp = Kh + (size_t)bh * SEQ * 64;
    const unsigned short* Vp = Vt + (size_t)bh * 64 * SEQ;

    bf16x8 aq[2];
    aq[0] = *reinterpret_cast<const bf16x8*>(Qp + (size_t)(qb + ln15) * 64 + g * 8);
    aq[1] = *reinterpret_cast<const bf16x8*>(Qp + (size_t)(qb + ln15) * 64 + 32 + g * 8);

    f32x4 oacc[4] = {};
    float m_i[4], l_i[4];
    #pragma unroll
    for (int j = 0; j < 4; ++j) { m_i[j] = -INFINITY; l_i[j] = 0.f; }

    const int kend = qb + 15;
    for (int kb = 0; kb <= kend; kb += 32) {
        const f32x4 z = {};
        f32x4 s0, s1 = z;
        {
            bf16x8 b0 = *reinterpret_cast<const bf16x8*>(Kp + (size_t)(kb + ln15) * 64 + g * 8);
            bf16x8 b1 = *reinterpret_cast<const bf16x8*>(Kp + (size_t)(kb + ln15) * 64 + 32 + g * 8);
            s0 = __builtin_amdgcn_mfma_f32_16x16x32_bf16(aq[0], b0, z, 0, 0, 0);
            s0 = __builtin_amdgcn_mfma_f32_16x16x32_bf16(aq[1], b1, s0, 0, 0, 0);
        }
        const bool t1 = (kb + 16) <= kend;
        if (t1) {
            bf16x8 b0 = *reinterpret_cast<const bf16x8*>(Kp + (size_t)(kb + 16 + ln15) * 64 + g * 8);
            bf16x8 b1 = *reinterpret_cast<const bf16x8*>(Kp + (size_t)(kb + 16 + ln15) * 64 + 32 + g * 8);
            s1 = __builtin_amdgcn_mfma_f32_16x16x32_bf16(aq[0], b0, z, 0, 0, 0);
            s1 = __builtin_amdgcn_mfma_f32_16x16x32_bf16(aq[1], b1, s1, 0, 0, 0);
        }
        float p0[4], p1[4], alpha[4];
        #pragma unroll
        for (int j = 0; j < 4; ++j) {
            int qg = qb + g * 4 + j;
            float v0 = s0[j] * 0.125f;
            if (kb + ln15 > qg) v0 = -INFINITY;
            float v1 = -INFINITY;
            if (t1) {
                v1 = s1[j] * 0.125f;
                if (kb + 16 + ln15 > qg) v1 = -INFINITY;
            }
            float mx = fmaxf(v0, v1);
            #pragma unroll
            for (int off = 1; off < 16; off <<= 1)
                mx = fmaxf(mx, __shfl_xor(mx, off));
            float mnew = fmaxf(m_i[j], mx);
            alpha[j] = expf(m_i[j] - mnew);           // -inf - finite -> 0
            p0[j] = expf(v0 - mnew);
            p1[j] = t1 ? expf(v1 - mnew) : 0.f;
            float rs = p0[j] + p1[j];
            #pragma unroll
            for (int off = 1; off < 16; off <<= 1)
                rs += __shfl_xor(rs, off);
            l_i[j] = l_i[j] * alpha[j] + rs;
            m_i[j] = mnew;
        }
        #pragma unroll
        for (int c = 0; c < 4; ++c)
            #pragma unroll
            for (int j = 0; j < 4; ++j)
                oacc[c][j] *= alpha[j];
        // P (f32, q rows on lane-groups) -> LDS -> A-fragment (q rows on ln15)
        #pragma unroll
        for (int j = 0; j < 4; ++j) {
            Plds[(g * 4 + j) * 32 + ln15] = f2bf(p0[j]);
            Plds[(g * 4 + j) * 32 + 16 + ln15] = f2bf(p1[j]);
        }
        __syncthreads();
        bf16x8 ap = *reinterpret_cast<const bf16x8*>(&Plds[ln15 * 32 + g * 8]);
        #pragma unroll
        for (int c = 0; c < 4; ++c) {
            bf16x8 bv = *reinterpret_cast<const bf16x8*>(
                Vp + (size_t)(c * 16 + ln15) * SEQ + kb + g * 8);
            oacc[c] = __builtin_amdgcn_mfma_f32_16x16x32_bf16(ap, bv, oacc[c], 0, 0, 0);
        }
        __syncthreads();
    }
    float inv[4];
    #pragma unroll
    for (int j = 0; j < 4; ++j) inv[j] = 1.f / l_i[j];
    int b = bh >> 4, h = bh & 15;
    #pragma unroll
    for (int c = 0; c < 4; ++c)
        #pragma unroll
        for (int j = 0; j < 4; ++j) {
            int s = qb + g * 4 + j;
            Out[((size_t)(b * SEQ + s)) * DM + h * 64 + c * 16 + ln15] =
                f2bf(oacc[c][j] * inv[j]);
        }
}

extern "C" void kernel_launch(void* const* d_in, const int* in_sizes, int n_in,
                              void* d_out, int out_size, void* d_ws, size_t ws_size,
                              hipStream_t stream) {
    const float* x = (const float*)d_in[0];
    const int* pos = (const int*)d_in[1];
    const float* Wq = (const float*)d_in[2];
    const float* Wk = (const float*)d_in[3];
    const float* Wv = (const float*)d_in[4];
    const float* Wo = (const float*)d_in[5];
    float* out = (float*)d_out;

    char* ws = (char*)d_ws;
    const size_t MB = 1024 * 1024;
    unsigned short* xb  = (unsigned short*)(ws + 0 * MB);
    unsigned short* wqb = (unsigned short*)(ws + 8 * MB);
    unsigned short* wkb = (unsigned short*)(ws + 10 * MB);
    unsigned short* wvb = (unsigned short*)(ws + 12 * MB);
    unsigned short* wob = (unsigned short*)(ws + 14 * MB);
    unsigned short* qt  = (unsigned short*)(ws + 16 * MB);
    unsigned short* kt  = (unsigned short*)(ws + 24 * MB);
    unsigned short* vt  = (unsigned short*)(ws + 32 * MB);
    unsigned short* qh  = (unsigned short*)(ws + 40 * MB);
    unsigned short* kh  = (unsigned short*)(ws + 48 * MB);
    unsigned short* vtr = (unsigned short*)(ws + 56 * MB);
    unsigned short* att = (unsigned short*)(ws + 64 * MB);

    cvt_f32_bf16<<<4096, 256, 0, stream>>>(x, xb, 1048576);
    cvt_f32_bf16<<<1024, 256, 0, stream>>>(Wq, wqb, 262144);
    cvt_f32_bf16<<<1024, 256, 0, stream>>>(Wk, wkb, 262144);
    cvt_f32_bf16<<<1024, 256, 0, stream>>>(Wv, wvb, 262144);
    cvt_f32_bf16<<<1024, 256, 0, stream>>>(Wo, wob, 262144);

    dim3 ggrid(8, 32);
    gemm_bt<1><<<ggrid, 256, 0, stream>>>(xb, wqb, qt, 4096, 1024, 1024);
    gemm_bt<1><<<ggrid, 256, 0, stream>>>(xb, wkb, kt, 4096, 1024, 1024);
    gemm_bt<1><<<ggrid, 256, 0, stream>>>(xb, wvb, vt, 4096, 1024, 1024);

    rope_kernel<<<4096, 256, 0, stream>>>(qt, kt, pos, qh, kh);
    vtrans_kernel<<<1024, 256, 0, stream>>>(vt, vtr);

    attn_kernel<<<4096, 64, 0, stream>>>(qh, kh, vtr, att);

    gemm_bt<0><<<ggrid, 256, 0, stream>>>(att, wob, out, 4096, 1024, 1024);
}

// Round 2
// 215.094 us; speedup vs baseline: 1.6857x; 1.6857x over previous
//
#include <hip/hip_runtime.h>
#include <hip/hip_bf16.h>
#include <cstdint>
#include <cmath>

#define SEQ 2048
#define NH 16
#define DM 1024
#define BATCH 2

typedef short bf16x8 __attribute__((ext_vector_type(8)));
typedef float f32x4 __attribute__((ext_vector_type(4)));
typedef const void __attribute__((address_space(1)))* gas_t;
typedef void __attribute__((address_space(3)))* las_t;

#if __has_builtin(__builtin_amdgcn_exp2f)
#define EXP2(x) __builtin_amdgcn_exp2f(x)
#else
#define EXP2(x) __expf((x) * 0.6931471805599453f)
#endif

// Q prescale: (1/sqrt(64)) * log2(e) so scores are already in log2 domain
#define QSCALE 0.18033688011112042f

static __device__ __forceinline__ unsigned short f2bf(float f) {
    union { __hip_bfloat16 h; unsigned short u; } cv;
    cv.h = __float2bfloat16(f);
    return cv.u;
}
static __device__ __forceinline__ float bf2f(unsigned short u) {
    union { unsigned short u; __hip_bfloat16 h; } cv;
    cv.u = u;
    return __bfloat162float(cv.h);
}

static __device__ __forceinline__ void gload_lds16(const void* g, void* l) {
    __builtin_amdgcn_global_load_lds(
        reinterpret_cast<gas_t>(reinterpret_cast<uintptr_t>(g)),
        reinterpret_cast<las_t>(reinterpret_cast<uintptr_t>(l)),
        16, 0, 0);
}

// ---------------- fp32 -> bf16 convert ----------------
__global__ void cvt_f32_bf16(const float* __restrict__ src,
                             unsigned short* __restrict__ dst, int n4) {
    int i = blockIdx.x * blockDim.x + threadIdx.x;
    if (i >= n4) return;
    float4 v = reinterpret_cast<const float4*>(src)[i];
    ushort4 o;
    o.x = f2bf(v.x); o.y = f2bf(v.y); o.z = f2bf(v.z); o.w = f2bf(v.w);
    reinterpret_cast<ushort4*>(dst)[i] = o;
}

// ---------------- bf16 GEMM: C[M][N] = A[M][K] * B[N][K]^T ----------------
template<int OUT_BF16>
__global__ __launch_bounds__(256) void gemm_bt(
    const unsigned short* __restrict__ A,
    const unsigned short* __restrict__ B,
    void* __restrict__ C, int M, int N, int K) {
    __shared__ unsigned short As[128 * 32];
    __shared__ unsigned short Bs[128 * 32];
    const int tid = threadIdx.x;
    const int lane = tid & 63, wid = tid >> 6;
    const int wr = wid >> 1, wc = wid & 1;
    const int ln15 = lane & 15, kq = lane >> 4;
    const int bm = blockIdx.y, bn = blockIdx.x;

    f32x4 acc[4][4] = {};
    const int nk = K >> 5;
    for (int kt = 0; kt < nk; ++kt) {
        #pragma unroll
        for (int i = 0; i < 2; ++i) {
            int c = i * 256 + tid;
            int row = c >> 2, k8 = (c & 3) << 3;
            size_t gofsA = (size_t)(bm * 128 + row) * K + kt * 32 + k8;
            size_t gofsB = (size_t)(bn * 128 + row) * K + kt * 32 + k8;
            unsigned ldsoff = (unsigned)(i * 256 + wid * 64) * 16;  // wave-uniform
            gload_lds16(A + gofsA, (char*)As + ldsoff);
            gload_lds16(B + gofsB, (char*)Bs + ldsoff);
        }
        __syncthreads();
        bf16x8 af[4], bf[4];
        #pragma unroll
        for (int m = 0; m < 4; ++m)
            af[m] = *reinterpret_cast<const bf16x8*>(&As[(wr * 64 + m * 16 + ln15) * 32 + kq * 8]);
        #pragma unroll
        for (int n = 0; n < 4; ++n)
            bf[n] = *reinterpret_cast<const bf16x8*>(&Bs[(wc * 64 + n * 16 + ln15) * 32 + kq * 8]);
        #pragma unroll
        for (int m = 0; m < 4; ++m)
            #pragma unroll
            for (int n = 0; n < 4; ++n)
                acc[m][n] = __builtin_amdgcn_mfma_f32_16x16x32_bf16(af[m], bf[n], acc[m][n], 0, 0, 0);
        __syncthreads();
    }
    #pragma unroll
    for (int m = 0; m < 4; ++m) {
        #pragma unroll
        for (int n = 0; n < 4; ++n) {
            int col = bn * 128 + wc * 64 + n * 16 + ln15;
            #pragma unroll
            for (int j = 0; j < 4; ++j) {
                int row = bm * 128 + wr * 64 + m * 16 + kq * 4 + j;
                if constexpr (OUT_BF16 != 0)
                    ((unsigned short*)C)[(size_t)row * N + col] = f2bf(acc[m][n][j]);
                else
                    ((float*)C)[(size_t)row * N + col] = acc[m][n][j];
            }
        }
    }
}

// ---------------- RoPE cos/sin table: [S][32] float2 ----------------
__global__ __launch_bounds__(256) void rope_table(const int* __restrict__ pos,
                                                  float2* __restrict__ tab) {
    int idx = blockIdx.x * 256 + threadIdx.x;  // s*32 + i
    int s = idx >> 5, i = idx & 31;
    float fpos = (float)pos[s];
    float freq = exp2f(-(float)i * (13.287712379549449f / 32.0f));  // theta^(-i/32)
    float ang = fpos * freq, sn, cs;
    sincosf(ang, &sn, &cs);
    tab[idx] = make_float2(cs, sn);
}

// ---------------- RoPE + split qkv[B*S][3072] -> Qh,Kh [B,H,S,64] ----------------
// Q additionally scaled by QSCALE (log2e/8) so attn uses exp2 directly.
__global__ __launch_bounds__(256) void rope_kernel(
    const unsigned short* __restrict__ qkv, const float2* __restrict__ tab,
    unsigned short* __restrict__ Qh, unsigned short* __restrict__ Kh) {
    int bs = blockIdx.x;            // b*SEQ + s
    int b = bs >> 11, s = bs & (SEQ - 1);
    int t = threadIdx.x;
    #pragma unroll
    for (int p = t; p < 512; p += 256) {
        int h = p >> 5, i = p & 31;
        float2 cs = tab[(s << 5) + i];
        size_t src = (size_t)bs * 3072 + h * 64 + 2 * i;
        size_t dst = ((size_t)(b * NH + h) * SEQ + s) * 64 + 2 * i;
        ushort2 qv = *reinterpret_cast<const ushort2*>(qkv + src);
        float q0 = bf2f(qv.x), q1 = bf2f(qv.y);
        ushort2 qo;
        qo.x = f2bf((q0 * cs.x - q1 * cs.y) * QSCALE);
        qo.y = f2bf((q1 * cs.x + q0 * cs.y) * QSCALE);
        *reinterpret_cast<ushort2*>(Qh + dst) = qo;
        ushort2 kv = *reinterpret_cast<const ushort2*>(qkv + src + 1024);
        float k0 = bf2f(kv.x), k1 = bf2f(kv.y);
        ushort2 ko;
        ko.x = f2bf(k0 * cs.x - k1 * cs.y);
        ko.y = f2bf(k1 * cs.x + k0 * cs.y);
        *reinterpret_cast<ushort2*>(Kh + dst) = ko;
    }
}

// ---------------- V: qkv cols 2048.. -> [B,H,64,S] (tiled transpose) ----------------
__global__ __launch_bounds__(256) void vtrans_kernel(
    const unsigned short* __restrict__ qkv, unsigned short* __restrict__ Vo) {
    __shared__ unsigned short tile[64][65];
    int blk = blockIdx.x;           // (b*NH + h)*32 + st
    int st = blk & 31, bh = blk >> 5;
    int sb = st * 64;
    int t = threadIdx.x;
    int b = bh >> 4, h = bh & 15;
    #pragma unroll
    for (int u = t; u < 1024; u += 256) {
        int sl = u >> 4, d4 = (u & 15) << 2;
        ushort4 v = *reinterpret_cast<const ushort4*>(
            qkv + (size_t)(b * SEQ + sb + sl) * 3072 + 2048 + h * 64 + d4);
        tile[sl][d4] = v.x; tile[sl][d4 + 1] = v.y;
        tile[sl][d4 + 2] = v.z; tile[sl][d4 + 3] = v.w;
    }
    __syncthreads();
    #pragma unroll
    for (int u = t; u < 1024; u += 256) {
        int d = u >> 4, s4 = (u & 15) << 2;
        ushort4 o;
        o.x = tile[s4][d]; o.y = tile[s4 + 1][d];
        o.z = tile[s4 + 2][d]; o.w = tile[s4 + 3][d];
        *reinterpret_cast<ushort4*>(Vo + ((size_t)bh * 64 + d) * SEQ + sb + s4) = o;
    }
}

// ---------------- causal flash attention (no-max unnormalized softmax) ----------
template<bool MASKED>
static __device__ __forceinline__ void attn_tile(
    int kb, int qb, int kend, int ln15, int g,
    const unsigned short* __restrict__ Kp, const unsigned short* __restrict__ Vp,
    unsigned short* __restrict__ P, const bf16x8& aq0, const bf16x8& aq1,
    f32x4* oacc, float* lsum) {
    const f32x4 z = {};
    f32x4 s0, s1 = z;
    {
        bf16x8 b0 = *reinterpret_cast<const bf16x8*>(Kp + (size_t)(kb + ln15) * 64 + g * 8);
        bf16x8 b1 = *reinterpret_cast<const bf16x8*>(Kp + (size_t)(kb + ln15) * 64 + 32 + g * 8);
        s0 = __builtin_amdgcn_mfma_f32_16x16x32_bf16(aq0, b0, z, 0, 0, 0);
        s0 = __builtin_amdgcn_mfma_f32_16x16x32_bf16(aq1, b1, s0, 0, 0, 0);
    }
    const bool t1 = !MASKED || (kb + 16 <= kend);
    if (t1) {
        bf16x8 c0 = *reinterpret_cast<const bf16x8*>(Kp + (size_t)(kb + 16 + ln15) * 64 + g * 8);
        bf16x8 c1 = *reinterpret_cast<const bf16x8*>(Kp + (size_t)(kb + 16 + ln15) * 64 + 32 + g * 8);
        s1 = __builtin_amdgcn_mfma_f32_16x16x32_bf16(aq0, c0, z, 0, 0, 0);
        s1 = __builtin_amdgcn_mfma_f32_16x16x32_bf16(aq1, c1, s1, 0, 0, 0);
    }
    #pragma unroll
    for (int j = 0; j < 4; ++j) {
        float v0 = EXP2(s0[j]);
        float v1 = t1 ? EXP2(s1[j]) : 0.f;
        if (MASKED) {
            int qg = qb + g * 4 + j;
            if (kb + ln15 > qg) v0 = 0.f;
            if (kb + 16 + ln15 > qg) v1 = 0.f;
        }
        lsum[j] += v0 + v1;
        P[(g * 4 + j) * 40 + ln15] = f2bf(v0);
        P[(g * 4 + j) * 40 + 16 + ln15] = f2bf(v1);
    }
    asm volatile("s_waitcnt lgkmcnt(0)" ::: "memory");
    bf16x8 ap = *reinterpret_cast<const bf16x8*>(&P[ln15 * 40 + g * 8]);
    #pragma unroll
    for (int c = 0; c < 4; ++c) {
        bf16x8 bv = *reinterpret_cast<const bf16x8*>(
            Vp + (size_t)(c * 16 + ln15) * SEQ + kb + g * 8);
        oacc[c] = __builtin_amdgcn_mfma_f32_16x16x32_bf16(ap, bv, oacc[c], 0, 0, 0);
    }
}

// 4 waves/block, each wave owns one 16-row q-tile; no cross-wave sharing, no barriers.
// Work-balanced tile assignment: block's 4 tiles sum to constant causal depth.
__global__ __launch_bounds__(256) void attn_kernel(
    const unsigned short* __restrict__ Qh, const unsigned short* __restrict__ Kh,
    const unsigned short* __restrict__ Vt, unsigned short* __restrict__ Out) {
    __shared__ unsigned short Plds[4][16 * 40];
    const int wid = threadIdx.x >> 6;
    const int lane = threadIdx.x & 63;
    const int ln15 = lane & 15, g = lane >> 4;
    const int bh = blockIdx.x >> 5;          // 0..31
    const int u = blockIdx.x & 31;           // 0..31
    const int qt = (wid < 2) ? (2 * u + wid) : (127 - 2 * u - (wid - 2));
    const int qb = qt * 16;
    unsigned short* P = Plds[wid];

    const unsigned short* Qp = Qh + (size_t)bh * SEQ * 64;
    const unsigned short* Kp = Kh + (size_t)bh * SEQ * 64;
    const unsigned short* Vp = Vt + (size_t)bh * 64 * SEQ;

    bf16x8 aq0 = *reinterpret_cast<const bf16x8*>(Qp + (size_t)(qb + ln15) * 64 + g * 8);
    bf16x8 aq1 = *reinterpret_cast<const bf16x8*>(Qp + (size_t)(qb + ln15) * 64 + 32 + g * 8);

    f32x4 oacc[4] = {};
    float lsum[4] = {0.f, 0.f, 0.f, 0.f};

    const int kend = qb + 15;
    const int kb_full = (qb >= 31) ? ((((qb - 31) >> 5) << 5) + 32) : 0;
    for (int kb = 0; kb < kb_full; kb += 32)
        attn_tile<false>(kb, qb, kend, ln15, g, Kp, Vp, P, aq0, aq1, oacc, lsum);
    attn_tile<true>(kb_full, qb, kend, ln15, g, Kp, Vp, P, aq0, aq1, oacc, lsum);

    float inv[4];
    #pragma unroll
    for (int j = 0; j < 4; ++j) {
        float r = lsum[j];
        #pragma unroll
        for (int off = 1; off < 16; off <<= 1)
            r += __shfl_xor(r, off);
        inv[j] = 1.f / r;
    }
    int b = bh >> 4, h = bh & 15;
    #pragma unroll
    for (int c = 0; c < 4; ++c)
        #pragma unroll
        for (int j = 0; j < 4; ++j) {
            int s = qb + g * 4 + j;
            Out[((size_t)(b * SEQ + s)) * DM + h * 64 + c * 16 + ln15] =
                f2bf(oacc[c][j] * inv[j]);
        }
}

extern "C" void kernel_launch(void* const* d_in, const int* in_sizes, int n_in,
                              void* d_out, int out_size, void* d_ws, size_t ws_size,
                              hipStream_t stream) {
    const float* x = (const float*)d_in[0];
    const int* pos = (const int*)d_in[1];
    const float* Wq = (const float*)d_in[2];
    const float* Wk = (const float*)d_in[3];
    const float* Wv = (const float*)d_in[4];
    const float* Wo = (const float*)d_in[5];
    float* out = (float*)d_out;

    char* ws = (char*)d_ws;
    const size_t MB = 1024 * 1024;
    unsigned short* xb   = (unsigned short*)(ws + 0 * MB);
    unsigned short* wqkv = (unsigned short*)(ws + 8 * MB);   // wq|wk|wv contiguous
    unsigned short* wob  = (unsigned short*)(ws + 14 * MB);
    unsigned short* qkv  = (unsigned short*)(ws + 16 * MB);  // [4096][3072]
    float2*         tab  = (float2*)       (ws + 40 * MB);   // [2048][32]
    unsigned short* qh   = (unsigned short*)(ws + 41 * MB);
    unsigned short* kh   = (unsigned short*)(ws + 49 * MB);
    unsigned short* vtr  = (unsigned short*)(ws + 57 * MB);
    unsigned short* att  = (unsigned short*)(ws + 65 * MB);

    cvt_f32_bf16<<<4096, 256, 0, stream>>>(x, xb, 1048576);
    cvt_f32_bf16<<<1024, 256, 0, stream>>>(Wq, wqkv, 262144);
    cvt_f32_bf16<<<1024, 256, 0, stream>>>(Wk, wqkv + 1024 * 1024, 262144);
    cvt_f32_bf16<<<1024, 256, 0, stream>>>(Wv, wqkv + 2 * 1024 * 1024, 262144);
    cvt_f32_bf16<<<1024, 256, 0, stream>>>(Wo, wob, 262144);
    rope_table<<<256, 256, 0, stream>>>(pos, tab);

    gemm_bt<1><<<dim3(24, 32), 256, 0, stream>>>(xb, wqkv, qkv, 4096, 3072, 1024);

    rope_kernel<<<4096, 256, 0, stream>>>(qkv, tab, qh, kh);
    vtrans_kernel<<<1024, 256, 0, stream>>>(qkv, vtr);

    attn_kernel<<<1024, 256, 0, stream>>>(qh, kh, vtr, att);

    gemm_bt<0><<<dim3(8, 32), 256, 0, stream>>>(att, wob, out, 4096, 1024, 1024);
}

// Round 4
// 140.735 us; speedup vs baseline: 2.5764x; 1.5284x over previous
//
#include <hip/hip_runtime.h>
#include <hip/hip_bf16.h>
#include <cstdint>
#include <cmath>

#define SEQ 2048
#define NH 16
#define DM 1024
#define BATCH 2

typedef short bf16x8 __attribute__((ext_vector_type(8)));
typedef float f32x4 __attribute__((ext_vector_type(4)));
typedef const void __attribute__((address_space(1)))* gas_t;
typedef void __attribute__((address_space(3)))* las_t;

#if __has_builtin(__builtin_amdgcn_exp2f)
#define EXP2(x) __builtin_amdgcn_exp2f(x)
#else
#define EXP2(x) __expf((x) * 0.6931471805599453f)
#endif

// Q prescale: (1/sqrt(64)) * log2(e) so scores are already in log2 domain
#define QSCALE 0.18033688011112042f

static __device__ __forceinline__ unsigned short f2bf(float f) {
    union { __hip_bfloat16 h; unsigned short u; } cv;
    cv.h = __float2bfloat16(f);
    return cv.u;
}
static __device__ __forceinline__ float bf2f(unsigned short u) {
    union { unsigned short u; __hip_bfloat16 h; } cv;
    cv.u = u;
    return __bfloat162float(cv.h);
}

static __device__ __forceinline__ void gload_lds16(const void* g, void* l) {
    __builtin_amdgcn_global_load_lds(
        reinterpret_cast<gas_t>(reinterpret_cast<uintptr_t>(g)),
        reinterpret_cast<las_t>(reinterpret_cast<uintptr_t>(l)),
        16, 0, 0);
}

// ---------------- fp32 -> bf16 convert ----------------
__global__ void cvt_f32_bf16(const float* __restrict__ src,
                             unsigned short* __restrict__ dst, int n4) {
    int i = blockIdx.x * blockDim.x + threadIdx.x;
    if (i >= n4) return;
    float4 v = reinterpret_cast<const float4*>(src)[i];
    ushort4 o;
    o.x = f2bf(v.x); o.y = f2bf(v.y); o.z = f2bf(v.z); o.w = f2bf(v.w);
    reinterpret_cast<ushort4*>(dst)[i] = o;
}

// ---------------- bf16 GEMM: C[M][N] = A[M][K] * B[N][K]^T ----------------
template<int OUT_BF16>
__global__ __launch_bounds__(256) void gemm_bt(
    const unsigned short* __restrict__ A,
    const unsigned short* __restrict__ B,
    void* __restrict__ C, int M, int N, int K) {
    __shared__ unsigned short As[128 * 32];
    __shared__ unsigned short Bs[128 * 32];
    const int tid = threadIdx.x;
    const int lane = tid & 63, wid = tid >> 6;
    const int wr = wid >> 1, wc = wid & 1;
    const int ln15 = lane & 15, kq = lane >> 4;
    const int bm = blockIdx.y, bn = blockIdx.x;

    f32x4 acc[4][4] = {};
    const int nk = K >> 5;
    for (int kt = 0; kt < nk; ++kt) {
        #pragma unroll
        for (int i = 0; i < 2; ++i) {
            int c = i * 256 + tid;
            int row = c >> 2, k8 = (c & 3) << 3;
            size_t gofsA = (size_t)(bm * 128 + row) * K + kt * 32 + k8;
            size_t gofsB = (size_t)(bn * 128 + row) * K + kt * 32 + k8;
            unsigned ldsoff = (unsigned)(i * 256 + wid * 64) * 16;  // wave-uniform
            gload_lds16(A + gofsA, (char*)As + ldsoff);
            gload_lds16(B + gofsB, (char*)Bs + ldsoff);
        }
        __syncthreads();
        bf16x8 af[4], bf[4];
        #pragma unroll
        for (int m = 0; m < 4; ++m)
            af[m] = *reinterpret_cast<const bf16x8*>(&As[(wr * 64 + m * 16 + ln15) * 32 + kq * 8]);
        #pragma unroll
        for (int n = 0; n < 4; ++n)
            bf[n] = *reinterpret_cast<const bf16x8*>(&Bs[(wc * 64 + n * 16 + ln15) * 32 + kq * 8]);
        #pragma unroll
        for (int m = 0; m < 4; ++m)
            #pragma unroll
            for (int n = 0; n < 4; ++n)
                acc[m][n] = __builtin_amdgcn_mfma_f32_16x16x32_bf16(af[m], bf[n], acc[m][n], 0, 0, 0);
        __syncthreads();
    }
    #pragma unroll
    for (int m = 0; m < 4; ++m) {
        #pragma unroll
        for (int n = 0; n < 4; ++n) {
            int col = bn * 128 + wc * 64 + n * 16 + ln15;
            #pragma unroll
            for (int j = 0; j < 4; ++j) {
                int row = bm * 128 + wr * 64 + m * 16 + kq * 4 + j;
                if constexpr (OUT_BF16 != 0)
                    ((unsigned short*)C)[(size_t)row * N + col] = f2bf(acc[m][n][j]);
                else
                    ((float*)C)[(size_t)row * N + col] = acc[m][n][j];
            }
        }
    }
}

// ---------------- RoPE cos/sin table: [S][32] float2 ----------------
__global__ __launch_bounds__(256) void rope_table(const int* __restrict__ pos,
                                                  float2* __restrict__ tab) {
    int idx = blockIdx.x * 256 + threadIdx.x;  // s*32 + i
    int s = idx >> 5, i = idx & 31;
    float fpos = (float)pos[s];
    float freq = exp2f(-(float)i * (13.287712379549449f / 32.0f));  // theta^(-i/32)
    float ang = fpos * freq, sn, cs;
    sincosf(ang, &sn, &cs);
    tab[idx] = make_float2(cs, sn);
}

// ---------------- RoPE + split qkv[B*S][3072] -> Qh,Kh [B,H,S,64] ----------------
__global__ __launch_bounds__(256) void rope_kernel(
    const unsigned short* __restrict__ qkv, const float2* __restrict__ tab,
    unsigned short* __restrict__ Qh, unsigned short* __restrict__ Kh) {
    int bs = blockIdx.x;            // b*SEQ + s
    int b = bs >> 11, s = bs & (SEQ - 1);
    int t = threadIdx.x;
    #pragma unroll
    for (int p = t; p < 512; p += 256) {
        int h = p >> 5, i = p & 31;
        float2 cs = tab[(s << 5) + i];
        size_t src = (size_t)bs * 3072 + h * 64 + 2 * i;
        size_t dst = ((size_t)(b * NH + h) * SEQ + s) * 64 + 2 * i;
        ushort2 qv = *reinterpret_cast<const ushort2*>(qkv + src);
        float q0 = bf2f(qv.x), q1 = bf2f(qv.y);
        ushort2 qo;
        qo.x = f2bf((q0 * cs.x - q1 * cs.y) * QSCALE);
        qo.y = f2bf((q1 * cs.x + q0 * cs.y) * QSCALE);
        *reinterpret_cast<ushort2*>(Qh + dst) = qo;
        ushort2 kv = *reinterpret_cast<const ushort2*>(qkv + src + 1024);
        float k0 = bf2f(kv.x), k1 = bf2f(kv.y);
        ushort2 ko;
        ko.x = f2bf(k0 * cs.x - k1 * cs.y);
        ko.y = f2bf(k1 * cs.x + k0 * cs.y);
        *reinterpret_cast<ushort2*>(Kh + dst) = ko;
    }
}

// ---------------- V: qkv cols 2048.. -> [B,H,64,S] (tiled transpose) ----------------
__global__ __launch_bounds__(256) void vtrans_kernel(
    const unsigned short* __restrict__ qkv, unsigned short* __restrict__ Vo) {
    __shared__ unsigned short tile[64][65];
    int blk = blockIdx.x;           // (b*NH + h)*32 + st
    int st = blk & 31, bh = blk >> 5;
    int sb = st * 64;
    int t = threadIdx.x;
    int b = bh >> 4, h = bh & 15;
    #pragma unroll
    for (int u = t; u < 1024; u += 256) {
        int sl = u >> 4, d4 = (u & 15) << 2;
        ushort4 v = *reinterpret_cast<const ushort4*>(
            qkv + (size_t)(b * SEQ + sb + sl) * 3072 + 2048 + h * 64 + d4);
        tile[sl][d4] = v.x; tile[sl][d4 + 1] = v.y;
        tile[sl][d4 + 2] = v.z; tile[sl][d4 + 3] = v.w;
    }
    __syncthreads();
    #pragma unroll
    for (int u = t; u < 1024; u += 256) {
        int d = u >> 4, s4 = (u & 15) << 2;
        ushort4 o;
        o.x = tile[s4][d]; o.y = tile[s4 + 1][d];
        o.z = tile[s4 + 2][d]; o.w = tile[s4 + 3][d];
        *reinterpret_cast<ushort4*>(Vo + ((size_t)bh * 64 + d) * SEQ + sb + s4) = o;
    }
}

// ---------------- causal flash attention, LDS-staged K/V, double-buffered ------
// Block: 4 waves, 64 contiguous q rows (16/wave). K-tile 32x64 + Vt-tile 64x32
// staged via global_load_lds (linear dest, inverse-swizzled source), counted vmcnt.
__global__ __launch_bounds__(256) void attn_kernel(
    const unsigned short* __restrict__ Qh, const unsigned short* __restrict__ Kh,
    const unsigned short* __restrict__ Vt, unsigned short* __restrict__ Out) {
    __shared__ unsigned short Kb[2][32 * 64];   // [k][d], slot-swizzled
    __shared__ unsigned short Vb[2][64 * 32];   // [d][k], slot-swizzled
    __shared__ unsigned short Plds[4][16 * 40];

    const int tid = threadIdx.x;
    const int wid = tid >> 6, lane = tid & 63;
    const int ln15 = lane & 15, g = lane >> 4;
    const int bid = blockIdx.x;
    const int bh = bid & 31;
    const int band = 31 - (bid >> 5);           // longest-work-first
    const int qb = band * 64 + wid * 16;
    const int kend = qb + 15;
    const int nt = 2 * band + 2;                // 32-wide k-tiles for this block

    const unsigned short* Qp = Qh + (size_t)bh * SEQ * 64;
    const unsigned short* Kp = Kh + (size_t)bh * SEQ * 64;
    const unsigned short* Vp = Vt + (size_t)bh * 64 * SEQ;
    unsigned short* P = Plds[wid];

    // --- staging source offsets (linear LDS dest = tid*16B; swizzle on source) ---
    // K: LDS slot tid -> row k=tid>>3, slot=tid&7 holds d-block (slot ^ (k&7))
    const int ks_k = tid >> 3, ks_slot = tid & 7;
    const unsigned short* kSrc = Kp + (size_t)ks_k * 64 + ((ks_slot ^ (ks_k & 7)) << 3);
    // V: LDS slot tid -> row d=tid>>2, slot=tid&3 holds k-block (slot ^ ((d>>1)&3))
    const int vs_d = tid >> 2, vs_slot = tid & 3;
    const unsigned short* vSrc = Vp + (size_t)vs_d * SEQ + ((vs_slot ^ ((vs_d >> 1) & 3)) << 3);
    const unsigned wuBase = (unsigned)wid * 1024;  // wave-uniform LDS chunk base

    // --- compute-side LDS byte offsets (fixed per lane) ---
    const int r0 = ln15, r1 = ln15 + 16;
    const unsigned kOff0a = r0 * 128 + ((g ^ (r0 & 7)) << 4);
    const unsigned kOff0b = r0 * 128 + (((4 + g) ^ (r0 & 7)) << 4);
    const unsigned kOff1a = r1 * 128 + ((g ^ (r1 & 7)) << 4);
    const unsigned kOff1b = r1 * 128 + (((4 + g) ^ (r1 & 7)) << 4);
    unsigned vOff[4];
    #pragma unroll
    for (int c = 0; c < 4; ++c) {
        int d = c * 16 + ln15;
        vOff[c] = d * 64 + ((g ^ ((d >> 1) & 3)) << 4);
    }

    bf16x8 aq0 = *reinterpret_cast<const bf16x8*>(Qp + (size_t)(qb + ln15) * 64 + g * 8);
    bf16x8 aq1 = *reinterpret_cast<const bf16x8*>(Qp + (size_t)(qb + ln15) * 64 + 32 + g * 8);

    f32x4 oacc[4] = {};
    float lsum[4] = {0.f, 0.f, 0.f, 0.f};

    // prologue: stage tile 0 into buf 0
    gload_lds16(kSrc, (char*)Kb[0] + wuBase);
    gload_lds16(vSrc, (char*)Vb[0] + wuBase);

    for (int t = 0; t < nt; ++t) {
        const int kb = t << 5;
        const int cur = t & 1, nxt = cur ^ 1;
        // issue next tile's stage (clamped re-stage on last iter)
        {
            int tn = t + 1; if (tn > nt - 1) tn = nt - 1;
            size_t adv = (size_t)(tn << 5);
            gload_lds16(kSrc + adv * 64, (char*)Kb[nxt] + wuBase);
            gload_lds16(vSrc + adv, (char*)Vb[nxt] + wuBase);
        }
        asm volatile("s_waitcnt vmcnt(2)" ::: "memory");   // tile t staged (all waves do this)
        __builtin_amdgcn_s_barrier();

        if (kb <= kend) {
            const unsigned short* K0 = Kb[cur];
            const unsigned short* V0 = Vb[cur];
            const f32x4 z = {};
            bf16x8 b0 = *reinterpret_cast<const bf16x8*>((const char*)K0 + kOff0a);
            bf16x8 b1 = *reinterpret_cast<const bf16x8*>((const char*)K0 + kOff0b);
            bf16x8 c0 = *reinterpret_cast<const bf16x8*>((const char*)K0 + kOff1a);
            bf16x8 c1 = *reinterpret_cast<const bf16x8*>((const char*)K0 + kOff1b);
            f32x4 s0, s1;
            s0 = __builtin_amdgcn_mfma_f32_16x16x32_bf16(aq0, b0, z, 0, 0, 0);
            s0 = __builtin_amdgcn_mfma_f32_16x16x32_bf16(aq1, b1, s0, 0, 0, 0);
            s1 = __builtin_amdgcn_mfma_f32_16x16x32_bf16(aq0, c0, z, 0, 0, 0);
            s1 = __builtin_amdgcn_mfma_f32_16x16x32_bf16(aq1, c1, s1, 0, 0, 0);

            // Tile is fully causal only if its max k (kb+31) <= the wave's MIN
            // q-row (qb). Using kend (=qb+15) here was the round-3 bug: rows
            // below the wave max got acausal k contributions.
            const bool masked = (kb + 31) > qb;
            #pragma unroll
            for (int j = 0; j < 4; ++j) {
                float v0 = EXP2(s0[j]);
                float v1 = EXP2(s1[j]);
                if (masked) {
                    int qg = qb + g * 4 + j;
                    if (kb + ln15 > qg) v0 = 0.f;
                    if (kb + 16 + ln15 > qg) v1 = 0.f;
                }
                lsum[j] += v0 + v1;
                P[(g * 4 + j) * 40 + ln15] = f2bf(v0);
                P[(g * 4 + j) * 40 + 16 + ln15] = f2bf(v1);
            }
            asm volatile("s_waitcnt lgkmcnt(0)" ::: "memory");
            bf16x8 ap = *reinterpret_cast<const bf16x8*>(&P[ln15 * 40 + g * 8]);
            #pragma unroll
            for (int c = 0; c < 4; ++c) {
                bf16x8 bv = *reinterpret_cast<const bf16x8*>((const char*)V0 + vOff[c]);
                oacc[c] = __builtin_amdgcn_mfma_f32_16x16x32_bf16(ap, bv, oacc[c], 0, 0, 0);
            }
        }
        asm volatile("s_waitcnt lgkmcnt(0)" ::: "memory");  // all LDS reads of buf[cur] done
        __builtin_amdgcn_s_barrier();
    }

    float inv[4];
    #pragma unroll
    for (int j = 0; j < 4; ++j) {
        float r = lsum[j];
        #pragma unroll
        for (int off = 1; off < 16; off <<= 1)
            r += __shfl_xor(r, off);
        inv[j] = 1.f / r;
    }
    int b = bh >> 4, h = bh & 15;
    #pragma unroll
    for (int c = 0; c < 4; ++c)
        #pragma unroll
        for (int j = 0; j < 4; ++j) {
            int s = qb + g * 4 + j;
            Out[((size_t)(b * SEQ + s)) * DM + h * 64 + c * 16 + ln15] =
                f2bf(oacc[c][j] * inv[j]);
        }
}

extern "C" void kernel_launch(void* const* d_in, const int* in_sizes, int n_in,
                              void* d_out, int out_size, void* d_ws, size_t ws_size,
                              hipStream_t stream) {
    const float* x = (const float*)d_in[0];
    const int* pos = (const int*)d_in[1];
    const float* Wq = (const float*)d_in[2];
    const float* Wk = (const float*)d_in[3];
    const float* Wv = (const float*)d_in[4];
    const float* Wo = (const float*)d_in[5];
    float* out = (float*)d_out;

    char* ws = (char*)d_ws;
    const size_t MB = 1024 * 1024;
    unsigned short* xb   = (unsigned short*)(ws + 0 * MB);
    unsigned short* wqkv = (unsigned short*)(ws + 8 * MB);   // wq|wk|wv contiguous
    unsigned short* wob  = (unsigned short*)(ws + 14 * MB);
    unsigned short* qkv  = (unsigned short*)(ws + 16 * MB);  // [4096][3072]
    float2*         tab  = (float2*)       (ws + 40 * MB);   // [2048][32]
    unsigned short* qh   = (unsigned short*)(ws + 41 * MB);
    unsigned short* kh   = (unsigned short*)(ws + 49 * MB);
    unsigned short* vtr  = (unsigned short*)(ws + 57 * MB);
    unsigned short* att  = (unsigned short*)(ws + 65 * MB);

    cvt_f32_bf16<<<4096, 256, 0, stream>>>(x, xb, 1048576);
    cvt_f32_bf16<<<1024, 256, 0, stream>>>(Wq, wqkv, 262144);
    cvt_f32_bf16<<<1024, 256, 0, stream>>>(Wk, wqkv + 1024 * 1024, 262144);
    cvt_f32_bf16<<<1024, 256, 0, stream>>>(Wv, wqkv + 2 * 1024 * 1024, 262144);
    cvt_f32_bf16<<<1024, 256, 0, stream>>>(Wo, wob, 262144);
    rope_table<<<256, 256, 0, stream>>>(pos, tab);

    gemm_bt<1><<<dim3(24, 32), 256, 0, stream>>>(xb, wqkv, qkv, 4096, 3072, 1024);

    rope_kernel<<<4096, 256, 0, stream>>>(qkv, tab, qh, kh);
    vtrans_kernel<<<1024, 256, 0, stream>>>(qkv, vtr);

    attn_kernel<<<1024, 256, 0, stream>>>(qh, kh, vtr, att);

    gemm_bt<0><<<dim3(8, 32), 256, 0, stream>>>(att, wob, out, 4096, 1024, 1024);
}